// Round 18
// baseline (529.685 us; speedup 1.0000x reference)
//
#include <hip/hip_runtime.h>
#include <hip/hip_bf16.h>
#include <math.h>

#define T_TOK 8192
#define DMODEL 1024
#define FFN 4096
#define NEXP 8
#define NSLOT (T_TOK * 2)
#define MAXT 136  // sum ceil(c_e/128) <= 16384/128 + 8 = 136

typedef _Float16 f16;
typedef _Float16 half8 __attribute__((ext_vector_type(8)));
typedef _Float16 half4 __attribute__((ext_vector_type(4)));
typedef float f32x4 __attribute__((ext_vector_type(4)));
typedef unsigned int u32;

__device__ __forceinline__ void gll16(const void* g, void* l) {
  __builtin_amdgcn_global_load_lds(
      (const __attribute__((address_space(1))) u32*)g,
      (__attribute__((address_space(3))) u32*)l, 16, 0, 0);
}

// exact-erf gelu via A&S 7.1.26 (max abs err 1.5e-7), ~10 VALU ops
__device__ __forceinline__ float gelu_fast(float v) {
  float x = fabsf(v) * 0.70710678118654752f;
  float t = 1.0f / (1.0f + 0.3275911f * x);
  float poly = ((((1.061405429f * t - 1.453152027f) * t + 1.421413741f) * t -
                 0.284496736f) * t + 0.254829592f) * t;
  float erf_ = 1.0f - poly * __expf(-x * x);
  erf_ = copysignf(erf_, v);
  return 0.5f * v * (1.0f + erf_);
}

__device__ __forceinline__ float gelu_exact(float v) {
  return 0.5f * v * (1.0f + erff(v * 0.70710678118654752f));
}

// ---- tm -> (expert, row0, nrows) from counts[8]; 128-row tiles ------------
__device__ __forceinline__ bool decode_tile(const int* __restrict__ counts,
                                            int tm, int& e, int& row0,
                                            int& nrows) {
  int acc = 0, off = 0;
#pragma unroll
  for (int i = 0; i < NEXP; i++) {
    int c = counts[i];
    int nt = (c + 127) >> 7;
    if (tm < acc + nt) {
      int lt = tm - acc;
      e = i; row0 = off + lt * 128; nrows = min(128, c - lt * 128);
      return true;
    }
    acc += nt; off += c;
  }
  return false;
}

// ---- 128r x 64c transpose+convert tile, 256-thread version ----------------
__device__ __forceinline__ void transq_tile256(const float* __restrict__ ip,
                                               f16* __restrict__ op, int R, int C,
                                               int r0, int c0, char* smemraw) {
  float* tile = (float*)smemraw;  // [128][64] w/ chunk skew, 32 KB
  int tid = threadIdx.x;
#pragma unroll
  for (int p = 0; p < 8; p++) {
    int idx = tid + p * 256;
    int row = idx >> 4, q = idx & 15;
    f32x4 v = *(const f32x4*)(ip + (size_t)(r0 + row) * C + c0 + q * 4);
    int qs = (q + (row >> 3)) & 15;
    *(f32x4*)(tile + row * 64 + qs * 4) = v;
  }
  __syncthreads();
#pragma unroll
  for (int p = 0; p < 4; p++) {
    int idx = tid + p * 256;
    int c = idx >> 4, b = idx & 15;
    half8 h;
#pragma unroll
    for (int i = 0; i < 8; i++) {
      int row = b * 8 + i;
      int qs = (((c >> 2) + b) & 15);
      h[i] = (f16)tile[row * 64 + qs * 4 + (c & 3)];
    }
    *(half8*)(op + (size_t)(c0 + c) * R + r0 + b * 8) = h;
  }
}

// ======== prepA: blocks [0,4096) = W_in transpose; rest = router + x cvt ===
__global__ __launch_bounds__(256) void prepA_k(
    const float* __restrict__ x, const float* __restrict__ Wr,
    const float* __restrict__ Wi,
    int* __restrict__ sel_e, float* __restrict__ sel_w,
    f16* __restrict__ xh, f16* __restrict__ WiT) {
  __shared__ __align__(16) char smem[32768];
  if (blockIdx.x < 4096) {
    int e = blockIdx.x >> 9;
    int idx = blockIdx.x & 511;
    int rt = idx >> 6, ct = idx & 63;  // R=1024 -> 8 rt ; C=4096 -> 64 ct
    transq_tile256(Wi + (size_t)e * DMODEL * FFN, WiT + (size_t)e * DMODEL * FFN,
                   DMODEL, FFN, rt * 128, ct * 64, smem);
  } else {
    int rb = blockIdx.x - 4096;
    int t = rb * 4 + (threadIdx.x >> 6);
    int lane = threadIdx.x & 63;
    const float* xp = x + (size_t)t * DMODEL;
    f16* xhp = xh + (size_t)t * DMODEL;
    float p[NEXP];
#pragma unroll
    for (int e = 0; e < NEXP; e++) p[e] = 0.f;
#pragma unroll
    for (int q = 0; q < 4; q++) {
      f32x4 xv = *(const f32x4*)(xp + q * 256 + lane * 4);
      half4 h;
      h[0] = (f16)xv[0]; h[1] = (f16)xv[1]; h[2] = (f16)xv[2]; h[3] = (f16)xv[3];
      *(half4*)(xhp + q * 256 + lane * 4) = h;
#pragma unroll
      for (int e = 0; e < NEXP; e++) {
        const f32x4 wv = *(const f32x4*)(Wr + e * DMODEL + q * 256 + lane * 4);
        p[e] += xv[0] * wv[0] + xv[1] * wv[1] + xv[2] * wv[2] + xv[3] * wv[3];
      }
    }
#pragma unroll
    for (int off = 32; off; off >>= 1) {
#pragma unroll
      for (int e = 0; e < NEXP; e++) p[e] += __shfl_xor(p[e], off);
    }
    if (lane == 0) {
      float l0 = -1e30f, l1 = -1e30f;
      int e0 = 0, e1 = 1;
#pragma unroll
      for (int e = 0; e < NEXP; e++) {
        if (p[e] > l0) { l1 = l0; e1 = e0; l0 = p[e]; e0 = e; }
        else if (p[e] > l1) { l1 = p[e]; e1 = e; }
      }
      float r = expf(l1 - l0);
      float inv = 1.f / (1.f + r);
      sel_e[t * 2] = e0;     sel_w[t * 2] = inv;
      sel_e[t * 2 + 1] = e1; sel_w[t * 2 + 1] = r * inv;
    }
  }
}

// ---- count64: LDS-aggregated, 512 global atomics total --------------------
__global__ __launch_bounds__(256) void count64_k(const int* __restrict__ sel_e,
                                                 int* __restrict__ counts) {
  __shared__ int lc[NEXP];
  int tid = threadIdx.x;
  if (tid < NEXP) lc[tid] = 0;
  __syncthreads();
  int v = sel_e[blockIdx.x * 256 + tid];
  atomicAdd(&lc[v], 1);
  __syncthreads();
  if (tid < NEXP) atomicAdd(&counts[tid], lc[tid]);
}

// ---------------- scatter (offs derived in-register from counts) -----------
__global__ __launch_bounds__(256) void scatter_k(
    const int* __restrict__ sel_e, const float* __restrict__ sel_w,
    const int* __restrict__ counts, int* fill,
    int* __restrict__ row_tok, float* __restrict__ row_w,
    int* __restrict__ inv) {
  int s = blockIdx.x * 256 + threadIdx.x;
  int e = sel_e[s];
  int offs = 0;
#pragma unroll
  for (int i = 0; i < NEXP; i++) offs += (i < e) ? counts[i] : 0;
  int pos = atomicAdd(&fill[e], 1);
  int r = offs + pos;
  row_tok[r] = s >> 1;
  row_w[r] = sel_w[s];
  inv[s] = r;
}

// ============ GEMM1 (+ tail-fused W_out transpose), R16 config ============
// 128x128, BK=64, 4 waves, single-buffer, 2 syncs/kt, zero-conflict XOR
// layout; wave-private barrier-free epilogue; NT H stores.
__global__ __launch_bounds__(256, 3) void gemm1_k(
    const f16* __restrict__ Xh, const f16* __restrict__ Wt,
    const float* __restrict__ b_in, f16* __restrict__ H,
    const int* __restrict__ meta,
    const float* __restrict__ Wo, f16* __restrict__ WoT) {
  __shared__ __align__(16) char smem[36864];  // staging 32K | epi 4x9216

  if (blockIdx.x >= MAXT * 32) {
    int bid = blockIdx.x - MAXT * 32;
    int e = bid >> 9;
    int idx = bid & 511;
    int rt = idx >> 4, ct = idx & 15;  // R=4096 -> 32 rt ; C=1024 -> 16 ct
    transq_tile256(Wo + (size_t)e * DMODEL * FFN, WoT + (size_t)e * DMODEL * FFN,
                   FFN, DMODEL, rt * 128, ct * 64, smem);
    return;
  }
  int bid2 = blockIdx.x;
  int xcd = bid2 & 7, bidx = bid2 >> 3;
  int wg = xcd * ((MAXT * 32) >> 3) + bidx;  // chunked-bijective XCD swizzle
  int tm = wg >> 5;            // slow: 32 consecutive wg share 256KB A panel
  int n0 = (wg & 31) * 128;
  int e, row0, nrows;
  if (!decode_tile(meta, tm, e, row0, nrows)) return;
  const int* row_tok = meta + 1024 + 2 * NSLOT;

  int tid = threadIdx.x, lane = tid & 63, wid = tid >> 6;
  int wrow = wid >> 1, wcol = wid & 1;
  int l15 = lane & 15, l4 = lane >> 4;

  u32 aoffs[4], boffs[4];
#pragma unroll
  for (int p = 0; p < 4; p++) {
    int L = tid + p * 256;
    int row = L >> 3, ch = L & 7;
    int cs = ch ^ (row & 7);
    aoffs[p] = (u32)(row_tok[min(row0 + row, NSLOT - 1)] * (DMODEL * 2) + cs * 16);
    boffs[p] = (u32)((e * FFN + n0 + row) * (DMODEL * 2) + cs * 16);
  }
  const char* gA = (const char*)Xh;
  const char* gB = (const char*)Wt;

  f32x4 acc[4][4];
#pragma unroll
  for (int m = 0; m < 4; m++)
#pragma unroll
    for (int n = 0; n < 4; n++) acc[m][n] = (f32x4)0.f;

  const int NT = DMODEL / 64;  // 16
  for (int kt = 0; kt < NT; ++kt) {
#pragma unroll
    for (int p = 0; p < 4; p++) {
      gll16(gA + aoffs[p], smem + (tid + p * 256) * 16);
      gll16(gB + boffs[p], smem + 16384 + (tid + p * 256) * 16);
      aoffs[p] += 128; boffs[p] += 128;
    }
    __syncthreads();  // drains vmcnt -> tile ready
#pragma unroll
    for (int s = 0; s < 2; s++) {
      int swz = ((s * 4 + l4) ^ (l15 & 7)) << 4;
      const char* pA = smem + (wrow * 64 + l15) * 128 + swz;
      const char* pB = smem + 16384 + (wcol * 64 + l15) * 128 + swz;
      half8 a[4], b[4];
#pragma unroll
      for (int i = 0; i < 4; i++) a[i] = *(const half8*)(pA + i * 2048);
#pragma unroll
      for (int j = 0; j < 4; j++) b[j] = *(const half8*)(pB + j * 2048);
#pragma unroll
      for (int i = 0; i < 4; i++)
#pragma unroll
        for (int j = 0; j < 4; j++)
          acc[i][j] = __builtin_amdgcn_mfma_f32_16x16x32_f16(a[i], b[j], acc[i][j], 0, 0, 0);
    }
    __syncthreads();  // all reads done before next stage overwrites
  }

  // wave-private epilogue (no barriers): gelu -> LDS [64 x 144B] -> NT stores
  char* wsm = smem + wid * 9216;
  float bias[4];
#pragma unroll
  for (int n = 0; n < 4; n++) bias[n] = b_in[e * FFN + n0 + wcol * 64 + n * 16 + l15];
#pragma unroll
  for (int m = 0; m < 4; m++)
#pragma unroll
    for (int n = 0; n < 4; n++)
#pragma unroll
      for (int j = 0; j < 4; j++) {
        int lrow = m * 16 + l4 * 4 + j;
        *(f16*)(wsm + lrow * 144 + (n * 16 + l15) * 2) =
            (f16)gelu_fast(acc[m][n][j] + bias[n]);
      }
#pragma unroll
  for (int p = 0; p < 8; ++p) {
    int lr = (lane >> 3) + p * 8;
    if (wrow * 64 + lr < nrows) {
      f32x4 v = *(const f32x4*)(wsm + lr * 144 + (lane & 7) * 16);
      __builtin_nontemporal_store(
          v, (f32x4*)(H + (size_t)(row0 + wrow * 64 + lr) * FFN + n0 +
                      wcol * 64 + (lane & 7) * 8));
    }
  }
}

// ============ GEMM2: wave-tile 128x64 A/B experiment ======================
// block 128x128, 2 waves (each 128 rows x 64 cols), BK=64, K-split 2.
// LDS bytes/FLOP = 0.75x of the 64x64-wave-tile structure.
__global__ __launch_bounds__(128, 2) void gemm2_k(
    const f16* __restrict__ H, const f16* __restrict__ Wt,
    const float* __restrict__ b_out, f16* __restrict__ Y0,
    f16* __restrict__ Y1, const int* __restrict__ meta) {
  int xcd = blockIdx.x & 7, bidx = blockIdx.x >> 3;
  int wg = xcd * (gridDim.x >> 3) + bidx;
  int tm = wg >> 4;            // slow
  int r4 = wg & 15;
  int n0 = (r4 & 7) * 128;     // fast: A panel reused across 8 blocks
  int ks = r4 >> 3;            // K half
  int e, row0, nrows;
  if (!decode_tile(meta, tm, e, row0, nrows)) return;

  __shared__ __align__(16) char smem[36864];  // staging A16K|B16K ; epi 2x18432

  int tid = threadIdx.x, lane = tid & 63, wid = tid >> 6;  // wid 0..1
  int wcol = wid;
  int l15 = lane & 15, l4 = lane >> 4;
  u32 k0b = (u32)(ks * (FFN / 2) * 2);   // byte offset of K half

  u32 aoffs[8], boffs[8];
#pragma unroll
  for (int p = 0; p < 8; p++) {
    int L = tid + p * 128;
    int row = L >> 3, ch = L & 7;
    int cs = ch ^ (row & 7);
    aoffs[p] = (u32)((u32)min(row0 + row, NSLOT - 1) * (FFN * 2) + k0b + cs * 16);
    boffs[p] = (u32)((u32)(e * DMODEL + n0 + row) * (FFN * 2) + k0b + cs * 16);
  }
  const char* gA = (const char*)H;
  const char* gB = (const char*)Wt;

  f32x4 acc[8][4];
#pragma unroll
  for (int m = 0; m < 8; m++)
#pragma unroll
    for (int n = 0; n < 4; n++) acc[m][n] = (f32x4)0.f;

  const int NT = (FFN / 2) / 64;  // 32
  for (int kt = 0; kt < NT; ++kt) {
#pragma unroll
    for (int p = 0; p < 8; p++) {
      gll16(gA + aoffs[p], smem + (tid + p * 128) * 16);
      gll16(gB + boffs[p], smem + 16384 + (tid + p * 128) * 16);
      aoffs[p] += 128; boffs[p] += 128;
    }
    __syncthreads();
#pragma unroll
    for (int s = 0; s < 2; s++) {
      int swz = ((s * 4 + l4) ^ (l15 & 7)) << 4;
      const char* pA = smem + l15 * 128 + swz;
      const char* pB = smem + 16384 + (wcol * 64 + l15) * 128 + swz;
      half8 a[8], b[4];
#pragma unroll
      for (int i = 0; i < 8; i++) a[i] = *(const half8*)(pA + i * 2048);
#pragma unroll
      for (int j = 0; j < 4; j++) b[j] = *(const half8*)(pB + j * 2048);
#pragma unroll
      for (int i = 0; i < 8; i++)
#pragma unroll
        for (int j = 0; j < 4; j++)
          acc[i][j] = __builtin_amdgcn_mfma_f32_16x16x32_f16(a[i], b[j], acc[i][j], 0, 0, 0);
    }
    __syncthreads();
  }

  // wave-private epilogue: (acc+bias) -> f16 LDS [128x144B] -> NT row stores
  f16* Y = ks ? Y1 : Y0;
  char* wsm = smem + wid * 18432;
  float bias[4];
#pragma unroll
  for (int n = 0; n < 4; n++)
    bias[n] = (ks == 0) ? b_out[e * DMODEL + n0 + wcol * 64 + n * 16 + l15] : 0.f;
#pragma unroll
  for (int m = 0; m < 8; m++)
#pragma unroll
    for (int n = 0; n < 4; n++)
#pragma unroll
      for (int j = 0; j < 4; j++) {
        int lrow = m * 16 + l4 * 4 + j;
        *(f16*)(wsm + lrow * 144 + (n * 16 + l15) * 2) =
            (f16)(acc[m][n][j] + bias[n]);
      }
#pragma unroll
  for (int p = 0; p < 16; ++p) {
    int lr = (lane >> 3) + p * 8;
    if (lr < nrows) {
      f32x4 v = *(const f32x4*)(wsm + lr * 144 + (lane & 7) * 16);
      __builtin_nontemporal_store(
          v, (f32x4*)(Y + (size_t)(row0 + lr) * DMODEL + n0 +
                      wcol * 64 + (lane & 7) * 8));
    }
  }
}

// ---------- combine: out[t] = w0*(Y0[r0]+Y1[r0]) + w1*(Y0[r1]+Y1[r1]) ------
__global__ __launch_bounds__(256) void combine_k(
    const f16* __restrict__ Y0, const f16* __restrict__ Y1,
    const int* __restrict__ inv, const float* __restrict__ row_w,
    float* __restrict__ out) {
  int t = blockIdx.x * 4 + (threadIdx.x >> 6);
  int lane = threadIdx.x & 63;
  int r0 = inv[2 * t], r1 = inv[2 * t + 1];
  float w0 = row_w[r0], w1 = row_w[r1];
  int d0 = lane * 16;
  const half8* a0 = (const half8*)(Y0 + (size_t)r0 * DMODEL + d0);
  const half8* a1 = (const half8*)(Y1 + (size_t)r0 * DMODEL + d0);
  const half8* b0 = (const half8*)(Y0 + (size_t)r1 * DMODEL + d0);
  const half8* b1 = (const half8*)(Y1 + (size_t)r1 * DMODEL + d0);
  float* op = out + (size_t)t * DMODEL + d0;
#pragma unroll
  for (int q = 0; q < 2; q++) {
    half8 x0 = a0[q], x1 = a1[q], y0 = b0[q], y1 = b1[q];
    float r[8];
#pragma unroll
    for (int i = 0; i < 8; i++)
      r[i] = w0 * ((float)x0[i] + (float)x1[i]) +
             w1 * ((float)y0[i] + (float)y1[i]);
    f32x4 v1 = {r[0], r[1], r[2], r[3]};
    f32x4 v2 = {r[4], r[5], r[6], r[7]};
    *(f32x4*)(op + q * 8) = v1;
    *(f32x4*)(op + q * 8 + 4) = v2;
  }
}

// ---------------- fallback (small workspace) -------------------------------
__global__ __launch_bounds__(256) void naive_k(
    const float* __restrict__ x, const float* __restrict__ W_in,
    const float* __restrict__ b_in, const float* __restrict__ W_out,
    const float* __restrict__ b_out, const int* __restrict__ sel_e,
    const float* __restrict__ sel_w, float* __restrict__ out) {
  int s = blockIdx.x;
  int t = s >> 1;
  int e = sel_e[s];
  float w = sel_w[s];
  __shared__ float xs[DMODEL];
  __shared__ float hs[FFN];
  int tid = threadIdx.x;
  for (int d = tid; d < DMODEL; d += 256) xs[d] = x[(size_t)t * DMODEL + d];
  __syncthreads();
  for (int f = tid; f < FFN; f += 256) {
    float a = b_in[e * FFN + f];
    const float* wp = W_in + (size_t)e * DMODEL * FFN + f;
    for (int d = 0; d < DMODEL; d++) a += xs[d] * wp[(size_t)d * FFN];
    hs[f] = gelu_exact(a);
  }
  __syncthreads();
  for (int d = tid; d < DMODEL; d += 256) {
    float a = b_out[e * DMODEL + d];
    const float* wp = W_out + (size_t)e * FFN * DMODEL + d;
    for (int f = 0; f < FFN; f++) a += hs[f] * wp[(size_t)f * DMODEL];
    atomicAdd(&out[(size_t)t * DMODEL + d], w * a);
  }
}

// ---------------- router-only (fallback path needs sel_e/sel_w) ------------
__global__ __launch_bounds__(256) void router_k(
    const float* __restrict__ x, const float* __restrict__ Wr,
    int* __restrict__ sel_e, float* __restrict__ sel_w) {
  int t = blockIdx.x * 4 + (threadIdx.x >> 6);
  int lane = threadIdx.x & 63;
  const float* xp = x + (size_t)t * DMODEL;
  float p[NEXP];
#pragma unroll
  for (int e = 0; e < NEXP; e++) p[e] = 0.f;
#pragma unroll
  for (int i = 0; i < DMODEL / 64; i++) {
    float xv = xp[lane + i * 64];
#pragma unroll
    for (int e = 0; e < NEXP; e++) p[e] += xv * Wr[e * DMODEL + lane + i * 64];
  }
#pragma unroll
  for (int off = 32; off; off >>= 1) {
#pragma unroll
    for (int e = 0; e < NEXP; e++) p[e] += __shfl_xor(p[e], off);
  }
  if (lane == 0) {
    float l0 = -1e30f, l1 = -1e30f;
    int e0 = 0, e1 = 1;
#pragma unroll
    for (int e = 0; e < NEXP; e++) {
      if (p[e] > l0) { l1 = l0; e1 = e0; l0 = p[e]; e0 = e; }
      else if (p[e] > l1) { l1 = p[e]; e1 = e; }
    }
    float r = expf(l1 - l0);
    float inv = 1.f / (1.f + r);
    sel_e[t * 2] = e0;     sel_w[t * 2] = inv;
    sel_e[t * 2 + 1] = e1; sel_w[t * 2 + 1] = r * inv;
  }
}

extern "C" void kernel_launch(void* const* d_in, const int* in_sizes, int n_in,
                              void* d_out, int out_size, void* d_ws, size_t ws_size,
                              hipStream_t stream) {
  const float* residual = (const float*)d_in[0];
  const float* W_router = (const float*)d_in[1];
  const float* W_in = (const float*)d_in[2];
  const float* b_in = (const float*)d_in[3];
  const float* W_out = (const float*)d_in[4];
  const float* b_out = (const float*)d_in[5];
  float* out = (float*)d_out;

  char* ws = (char*)d_ws;
  int* meta = (int*)ws;
  size_t off = (size_t)1 << 20;
  f16* Xh = (f16*)(ws + off); off += (size_t)T_TOK * DMODEL * 2;       // 16 MB
  f16* Wih = (f16*)(ws + off); off += (size_t)NEXP * DMODEL * FFN * 2; // 64 MB
  f16* Woh = (f16*)(ws + off); off += (size_t)NEXP * DMODEL * FFN * 2; // 64 MB
  f16* H = (f16*)(ws + off); off += (size_t)NSLOT * FFN * 2;           // 128 MB
  off += 65536;                                                        // OOB slack
  bool fast = ws_size >= off;

  // Y0/Y1 alias Wih (dead after gemm1): 2 x 16384 x 1024 f16 = 64 MB exactly
  f16* Y0 = Wih;
  f16* Y1 = Wih + (size_t)NSLOT * DMODEL;

  int* sel_e = meta + 1024;
  float* sel_w = (float*)(meta + 1024 + NSLOT);
  int* row_tok = meta + 1024 + 2 * NSLOT;
  float* row_w = (float*)(meta + 1024 + 3 * NSLOT);
  int* inv = meta + 1024 + 4 * NSLOT;

  if (fast) {
    hipMemsetAsync(meta, 0, 512, stream);  // counts[8] + fill[8]
    prepA_k<<<4096 + T_TOK / 4, 256, 0, stream>>>(
        residual, W_router, W_in, sel_e, sel_w, Xh, Wih);
    count64_k<<<NSLOT / 256, 256, 0, stream>>>(sel_e, meta);
    scatter_k<<<NSLOT / 256, 256, 0, stream>>>(sel_e, sel_w, meta, meta + 64,
                                               row_tok, row_w, inv);
    gemm1_k<<<MAXT * 32 + 4096, 256, 0, stream>>>(Xh, Wih, b_in, H, meta,
                                                  W_out, Woh);
    gemm2_k<<<MAXT * 16, 128, 0, stream>>>(H, Woh, b_out, Y0, Y1, meta);
    combine_k<<<T_TOK / 4, 256, 0, stream>>>(Y0, Y1, inv, row_w, out);
  } else {
    hipMemsetAsync(d_out, 0, (size_t)out_size * sizeof(float), stream);
    router_k<<<T_TOK / 4, 256, 0, stream>>>(residual, W_router, sel_e, sel_w);
    naive_k<<<NSLOT, 256, 0, stream>>>(residual, W_in, b_in, W_out, b_out,
                                       sel_e, sel_w, out);
  }
}

// Round 19
// 508.072 us; speedup vs baseline: 1.0425x; 1.0425x over previous
//
#include <hip/hip_runtime.h>
#include <hip/hip_bf16.h>
#include <math.h>

#define T_TOK 8192
#define DMODEL 1024
#define FFN 4096
#define NEXP 8
#define NSLOT (T_TOK * 2)
#define MAXT 136  // sum ceil(c_e/128) <= 16384/128 + 8 = 136

typedef _Float16 f16;
typedef _Float16 half8 __attribute__((ext_vector_type(8)));
typedef _Float16 half4 __attribute__((ext_vector_type(4)));
typedef float f32x4 __attribute__((ext_vector_type(4)));
typedef unsigned int u32;

__device__ __forceinline__ void gll16(const void* g, void* l) {
  __builtin_amdgcn_global_load_lds(
      (const __attribute__((address_space(1))) u32*)g,
      (__attribute__((address_space(3))) u32*)l, 16, 0, 0);
}

// exact-erf gelu via A&S 7.1.26 (max abs err 1.5e-7), ~10 VALU ops
__device__ __forceinline__ float gelu_fast(float v) {
  float x = fabsf(v) * 0.70710678118654752f;
  float t = 1.0f / (1.0f + 0.3275911f * x);
  float poly = ((((1.061405429f * t - 1.453152027f) * t + 1.421413741f) * t -
                 0.284496736f) * t + 0.254829592f) * t;
  float erf_ = 1.0f - poly * __expf(-x * x);
  erf_ = copysignf(erf_, v);
  return 0.5f * v * (1.0f + erf_);
}

__device__ __forceinline__ float gelu_exact(float v) {
  return 0.5f * v * (1.0f + erff(v * 0.70710678118654752f));
}

// ---- tm -> (expert, row0, nrows) from counts[8]; 128-row tiles ------------
__device__ __forceinline__ bool decode_tile(const int* __restrict__ counts,
                                            int tm, int& e, int& row0,
                                            int& nrows) {
  int acc = 0, off = 0;
#pragma unroll
  for (int i = 0; i < NEXP; i++) {
    int c = counts[i];
    int nt = (c + 127) >> 7;
    if (tm < acc + nt) {
      int lt = tm - acc;
      e = i; row0 = off + lt * 128; nrows = min(128, c - lt * 128);
      return true;
    }
    acc += nt; off += c;
  }
  return false;
}

// ---- 128r x 64c transpose+convert tile, 256-thread, regular stores --------
__device__ __forceinline__ void transq_tile256(const float* __restrict__ ip,
                                               f16* __restrict__ op, int R, int C,
                                               int r0, int c0, char* smemraw) {
  float* tile = (float*)smemraw;  // [128][64] w/ chunk skew, 32 KB
  int tid = threadIdx.x;
#pragma unroll
  for (int p = 0; p < 8; p++) {
    int idx = tid + p * 256;
    int row = idx >> 4, q = idx & 15;
    f32x4 v = *(const f32x4*)(ip + (size_t)(r0 + row) * C + c0 + q * 4);
    int qs = (q + (row >> 3)) & 15;
    *(f32x4*)(tile + row * 64 + qs * 4) = v;
  }
  __syncthreads();
#pragma unroll
  for (int p = 0; p < 4; p++) {
    int idx = tid + p * 256;
    int c = idx >> 4, b = idx & 15;
    half8 h;
#pragma unroll
    for (int i = 0; i < 8; i++) {
      int row = b * 8 + i;
      int qs = (((c >> 2) + b) & 15);
      h[i] = (f16)tile[row * 64 + qs * 4 + (c & 3)];
    }
    *(half8*)(op + (size_t)(c0 + c) * R + r0 + b * 8) = h;
  }
}

// ======== prepA: blocks [0,4096) = W_in transpose; rest = router + x cvt ===
__global__ __launch_bounds__(256) void prepA_k(
    const float* __restrict__ x, const float* __restrict__ Wr,
    const float* __restrict__ Wi,
    int* __restrict__ sel_e, float* __restrict__ sel_w,
    f16* __restrict__ xh, f16* __restrict__ WiT) {
  __shared__ __align__(16) char smem[32768];
  if (blockIdx.x < 4096) {
    int e = blockIdx.x >> 9;
    int idx = blockIdx.x & 511;
    int rt = idx >> 6, ct = idx & 63;  // R=1024 -> 8 rt ; C=4096 -> 64 ct
    transq_tile256(Wi + (size_t)e * DMODEL * FFN, WiT + (size_t)e * DMODEL * FFN,
                   DMODEL, FFN, rt * 128, ct * 64, smem);
  } else {
    int rb = blockIdx.x - 4096;
    int t = rb * 4 + (threadIdx.x >> 6);
    int lane = threadIdx.x & 63;
    const float* xp = x + (size_t)t * DMODEL;
    f16* xhp = xh + (size_t)t * DMODEL;
    float p[NEXP];
#pragma unroll
    for (int e = 0; e < NEXP; e++) p[e] = 0.f;
#pragma unroll
    for (int q = 0; q < 4; q++) {
      f32x4 xv = *(const f32x4*)(xp + q * 256 + lane * 4);
      half4 h;
      h[0] = (f16)xv[0]; h[1] = (f16)xv[1]; h[2] = (f16)xv[2]; h[3] = (f16)xv[3];
      *(half4*)(xhp + q * 256 + lane * 4) = h;
#pragma unroll
      for (int e = 0; e < NEXP; e++) {
        const f32x4 wv = *(const f32x4*)(Wr + e * DMODEL + q * 256 + lane * 4);
        p[e] += xv[0] * wv[0] + xv[1] * wv[1] + xv[2] * wv[2] + xv[3] * wv[3];
      }
    }
#pragma unroll
    for (int off = 32; off; off >>= 1) {
#pragma unroll
      for (int e = 0; e < NEXP; e++) p[e] += __shfl_xor(p[e], off);
    }
    if (lane == 0) {
      float l0 = -1e30f, l1 = -1e30f;
      int e0 = 0, e1 = 1;
#pragma unroll
      for (int e = 0; e < NEXP; e++) {
        if (p[e] > l0) { l1 = l0; e1 = e0; l0 = p[e]; e0 = e; }
        else if (p[e] > l1) { l1 = p[e]; e1 = e; }
      }
      float r = expf(l1 - l0);
      float inv = 1.f / (1.f + r);
      sel_e[t * 2] = e0;     sel_w[t * 2] = inv;
      sel_e[t * 2 + 1] = e1; sel_w[t * 2 + 1] = r * inv;
    }
  }
}

// ---- count64: LDS-aggregated, 512 global atomics total --------------------
__global__ __launch_bounds__(256) void count64_k(const int* __restrict__ sel_e,
                                                 int* __restrict__ counts) {
  __shared__ int lc[NEXP];
  int tid = threadIdx.x;
  if (tid < NEXP) lc[tid] = 0;
  __syncthreads();
  int v = sel_e[blockIdx.x * 256 + tid];
  atomicAdd(&lc[v], 1);
  __syncthreads();
  if (tid < NEXP) atomicAdd(&counts[tid], lc[tid]);
}

// ---------------- scatter (offs derived in-register from counts) -----------
__global__ __launch_bounds__(256) void scatter_k(
    const int* __restrict__ sel_e, const float* __restrict__ sel_w,
    const int* __restrict__ counts, int* fill,
    int* __restrict__ row_tok, float* __restrict__ row_w,
    int* __restrict__ inv) {
  int s = blockIdx.x * 256 + threadIdx.x;
  int e = sel_e[s];
  int offs = 0;
#pragma unroll
  for (int i = 0; i < NEXP; i++) offs += (i < e) ? counts[i] : 0;
  int pos = atomicAdd(&fill[e], 1);
  int r = offs + pos;
  row_tok[r] = s >> 1;
  row_w[r] = sel_w[s];
  inv[s] = r;
}

// ============ GEMM1 (+ tail-fused W_out transpose), best config ===========
// 128x128, BK=64, 4 waves, single-buffer, 2 syncs/kt, zero-conflict XOR
// layout; wave-private barrier-free epilogue; NT H stores.
__global__ __launch_bounds__(256, 3) void gemm1_k(
    const f16* __restrict__ Xh, const f16* __restrict__ Wt,
    const float* __restrict__ b_in, f16* __restrict__ H,
    const int* __restrict__ meta,
    const float* __restrict__ Wo, f16* __restrict__ WoT) {
  __shared__ __align__(16) char smem[36864];  // staging 32K | epi 4x9216

  if (blockIdx.x >= MAXT * 32) {
    int bid = blockIdx.x - MAXT * 32;
    int e = bid >> 9;
    int idx = bid & 511;
    int rt = idx >> 4, ct = idx & 15;  // R=4096 -> 32 rt ; C=1024 -> 16 ct
    transq_tile256(Wo + (size_t)e * DMODEL * FFN, WoT + (size_t)e * DMODEL * FFN,
                   FFN, DMODEL, rt * 128, ct * 64, smem);
    return;
  }
  int bid2 = blockIdx.x;
  int xcd = bid2 & 7, bidx = bid2 >> 3;
  int wg = xcd * ((MAXT * 32) >> 3) + bidx;  // chunked-bijective XCD swizzle
  int tm = wg >> 5;            // slow: 32 consecutive wg share 256KB A panel
  int n0 = (wg & 31) * 128;
  int e, row0, nrows;
  if (!decode_tile(meta, tm, e, row0, nrows)) return;
  const int* row_tok = meta + 1024 + 2 * NSLOT;

  int tid = threadIdx.x, lane = tid & 63, wid = tid >> 6;
  int wrow = wid >> 1, wcol = wid & 1;
  int l15 = lane & 15, l4 = lane >> 4;

  u32 aoffs[4], boffs[4];
#pragma unroll
  for (int p = 0; p < 4; p++) {
    int L = tid + p * 256;
    int row = L >> 3, ch = L & 7;
    int cs = ch ^ (row & 7);
    aoffs[p] = (u32)(row_tok[min(row0 + row, NSLOT - 1)] * (DMODEL * 2) + cs * 16);
    boffs[p] = (u32)((e * FFN + n0 + row) * (DMODEL * 2) + cs * 16);
  }
  const char* gA = (const char*)Xh;
  const char* gB = (const char*)Wt;

  f32x4 acc[4][4];
#pragma unroll
  for (int m = 0; m < 4; m++)
#pragma unroll
    for (int n = 0; n < 4; n++) acc[m][n] = (f32x4)0.f;

  const int NT = DMODEL / 64;  // 16
  for (int kt = 0; kt < NT; ++kt) {
#pragma unroll
    for (int p = 0; p < 4; p++) {
      gll16(gA + aoffs[p], smem + (tid + p * 256) * 16);
      gll16(gB + boffs[p], smem + 16384 + (tid + p * 256) * 16);
      aoffs[p] += 128; boffs[p] += 128;
    }
    __syncthreads();  // drains vmcnt -> tile ready
#pragma unroll
    for (int s = 0; s < 2; s++) {
      int swz = ((s * 4 + l4) ^ (l15 & 7)) << 4;
      const char* pA = smem + (wrow * 64 + l15) * 128 + swz;
      const char* pB = smem + 16384 + (wcol * 64 + l15) * 128 + swz;
      half8 a[4], b[4];
#pragma unroll
      for (int i = 0; i < 4; i++) a[i] = *(const half8*)(pA + i * 2048);
#pragma unroll
      for (int j = 0; j < 4; j++) b[j] = *(const half8*)(pB + j * 2048);
#pragma unroll
      for (int i = 0; i < 4; i++)
#pragma unroll
        for (int j = 0; j < 4; j++)
          acc[i][j] = __builtin_amdgcn_mfma_f32_16x16x32_f16(a[i], b[j], acc[i][j], 0, 0, 0);
    }
    __syncthreads();  // all reads done before next stage overwrites
  }

  // wave-private epilogue (no barriers): gelu -> LDS [64 x 144B] -> NT stores
  char* wsm = smem + wid * 9216;
  float bias[4];
#pragma unroll
  for (int n = 0; n < 4; n++) bias[n] = b_in[e * FFN + n0 + wcol * 64 + n * 16 + l15];
#pragma unroll
  for (int m = 0; m < 4; m++)
#pragma unroll
    for (int n = 0; n < 4; n++)
#pragma unroll
      for (int j = 0; j < 4; j++) {
        int lrow = m * 16 + l4 * 4 + j;
        *(f16*)(wsm + lrow * 144 + (n * 16 + l15) * 2) =
            (f16)gelu_fast(acc[m][n][j] + bias[n]);
      }
#pragma unroll
  for (int p = 0; p < 8; ++p) {
    int lr = (lane >> 3) + p * 8;
    if (wrow * 64 + lr < nrows) {
      f32x4 v = *(const f32x4*)(wsm + lr * 144 + (lane & 7) * 16);
      __builtin_nontemporal_store(
          v, (f32x4*)(H + (size_t)(row0 + wrow * 64 + lr) * FFN + n0 +
                      wcol * 64 + (lane & 7) * 8));
    }
  }
}

// ============ GEMM2: Y[ks][slot] = H @ W_out (+b_out on ks0), f16, no atomics
__global__ __launch_bounds__(256, 3) void gemm2_k(
    const f16* __restrict__ H, const f16* __restrict__ Wt,
    const float* __restrict__ b_out, f16* __restrict__ Y0,
    f16* __restrict__ Y1, const int* __restrict__ meta) {
  int xcd = blockIdx.x & 7, bidx = blockIdx.x >> 3;
  int wg = xcd * (gridDim.x >> 3) + bidx;
  int tm = wg >> 4;            // slow
  int r4 = wg & 15;
  int n0 = (r4 & 7) * 128;     // fast: A panel reused across 8 blocks
  int ks = r4 >> 3;            // K half
  int e, row0, nrows;
  if (!decode_tile(meta, tm, e, row0, nrows)) return;

  __shared__ __align__(16) char smem[36864];

  int tid = threadIdx.x, lane = tid & 63, wid = tid >> 6;
  int wrow = wid >> 1, wcol = wid & 1;
  int l15 = lane & 15, l4 = lane >> 4;
  u32 k0b = (u32)(ks * (FFN / 2) * 2);   // byte offset of K half

  u32 aoffs[4], boffs[4];
#pragma unroll
  for (int p = 0; p < 4; p++) {
    int L = tid + p * 256;
    int row = L >> 3, ch = L & 7;
    int cs = ch ^ (row & 7);
    aoffs[p] = (u32)((u32)min(row0 + row, NSLOT - 1) * (FFN * 2) + k0b + cs * 16);
    boffs[p] = (u32)((u32)(e * DMODEL + n0 + row) * (FFN * 2) + k0b + cs * 16);
  }
  const char* gA = (const char*)H;
  const char* gB = (const char*)Wt;

  f32x4 acc[4][4];
#pragma unroll
  for (int m = 0; m < 4; m++)
#pragma unroll
    for (int n = 0; n < 4; n++) acc[m][n] = (f32x4)0.f;

  const int NT = (FFN / 2) / 64;  // 32
  for (int kt = 0; kt < NT; ++kt) {
#pragma unroll
    for (int p = 0; p < 4; p++) {
      gll16(gA + aoffs[p], smem + (tid + p * 256) * 16);
      gll16(gB + boffs[p], smem + 16384 + (tid + p * 256) * 16);
      aoffs[p] += 128; boffs[p] += 128;
    }
    __syncthreads();
#pragma unroll
    for (int s = 0; s < 2; s++) {
      int swz = ((s * 4 + l4) ^ (l15 & 7)) << 4;
      const char* pA = smem + (wrow * 64 + l15) * 128 + swz;
      const char* pB = smem + 16384 + (wcol * 64 + l15) * 128 + swz;
      half8 a[4], b[4];
#pragma unroll
      for (int i = 0; i < 4; i++) a[i] = *(const half8*)(pA + i * 2048);
#pragma unroll
      for (int j = 0; j < 4; j++) b[j] = *(const half8*)(pB + j * 2048);
#pragma unroll
      for (int i = 0; i < 4; i++)
#pragma unroll
        for (int j = 0; j < 4; j++)
          acc[i][j] = __builtin_amdgcn_mfma_f32_16x16x32_f16(a[i], b[j], acc[i][j], 0, 0, 0);
    }
    __syncthreads();
  }

  // wave-private epilogue: (acc+bias) -> f16 LDS -> NT row stores to Y[ks]
  f16* Y = ks ? Y1 : Y0;
  char* wsm = smem + wid * 9216;
  float bias[4];
#pragma unroll
  for (int n = 0; n < 4; n++)
    bias[n] = (ks == 0) ? b_out[e * DMODEL + n0 + wcol * 64 + n * 16 + l15] : 0.f;
#pragma unroll
  for (int m = 0; m < 4; m++)
#pragma unroll
    for (int n = 0; n < 4; n++)
#pragma unroll
      for (int j = 0; j < 4; j++) {
        int lrow = m * 16 + l4 * 4 + j;
        *(f16*)(wsm + lrow * 144 + (n * 16 + l15) * 2) =
            (f16)(acc[m][n][j] + bias[n]);
      }
#pragma unroll
  for (int p = 0; p < 8; ++p) {
    int lr = (lane >> 3) + p * 8;
    if (wrow * 64 + lr < nrows) {
      f32x4 v = *(const f32x4*)(wsm + lr * 144 + (lane & 7) * 16);
      __builtin_nontemporal_store(
          v, (f32x4*)(Y + (size_t)(row0 + wrow * 64 + lr) * DMODEL + n0 +
                      wcol * 64 + (lane & 7) * 8));
    }
  }
}

// ---------- combine: out[t] = w0*(Y0[r0]+Y1[r0]) + w1*(Y0[r1]+Y1[r1]) ------
__global__ __launch_bounds__(256) void combine_k(
    const f16* __restrict__ Y0, const f16* __restrict__ Y1,
    const int* __restrict__ inv, const float* __restrict__ row_w,
    float* __restrict__ out) {
  int t = blockIdx.x * 4 + (threadIdx.x >> 6);
  int lane = threadIdx.x & 63;
  int r0 = inv[2 * t], r1 = inv[2 * t + 1];
  float w0 = row_w[r0], w1 = row_w[r1];
  int d0 = lane * 16;
  const half8* a0 = (const half8*)(Y0 + (size_t)r0 * DMODEL + d0);
  const half8* a1 = (const half8*)(Y1 + (size_t)r0 * DMODEL + d0);
  const half8* b0 = (const half8*)(Y0 + (size_t)r1 * DMODEL + d0);
  const half8* b1 = (const half8*)(Y1 + (size_t)r1 * DMODEL + d0);
  float* op = out + (size_t)t * DMODEL + d0;
#pragma unroll
  for (int q = 0; q < 2; q++) {
    half8 x0 = a0[q], x1 = a1[q], y0 = b0[q], y1 = b1[q];
    float r[8];
#pragma unroll
    for (int i = 0; i < 8; i++)
      r[i] = w0 * ((float)x0[i] + (float)x1[i]) +
             w1 * ((float)y0[i] + (float)y1[i]);
    f32x4 v1 = {r[0], r[1], r[2], r[3]};
    f32x4 v2 = {r[4], r[5], r[6], r[7]};
    *(f32x4*)(op + q * 8) = v1;
    *(f32x4*)(op + q * 8 + 4) = v2;
  }
}

// ---------------- fallback (small workspace) -------------------------------
__global__ __launch_bounds__(256) void naive_k(
    const float* __restrict__ x, const float* __restrict__ W_in,
    const float* __restrict__ b_in, const float* __restrict__ W_out,
    const float* __restrict__ b_out, const int* __restrict__ sel_e,
    const float* __restrict__ sel_w, float* __restrict__ out) {
  int s = blockIdx.x;
  int t = s >> 1;
  int e = sel_e[s];
  float w = sel_w[s];
  __shared__ float xs[DMODEL];
  __shared__ float hs[FFN];
  int tid = threadIdx.x;
  for (int d = tid; d < DMODEL; d += 256) xs[d] = x[(size_t)t * DMODEL + d];
  __syncthreads();
  for (int f = tid; f < FFN; f += 256) {
    float a = b_in[e * FFN + f];
    const float* wp = W_in + (size_t)e * DMODEL * FFN + f;
    for (int d = 0; d < DMODEL; d++) a += xs[d] * wp[(size_t)d * FFN];
    hs[f] = gelu_exact(a);
  }
  __syncthreads();
  for (int d = tid; d < DMODEL; d += 256) {
    float a = b_out[e * DMODEL + d];
    const float* wp = W_out + (size_t)e * FFN * DMODEL + d;
    for (int f = 0; f < FFN; f++) a += hs[f] * wp[(size_t)f * DMODEL];
    atomicAdd(&out[(size_t)t * DMODEL + d], w * a);
  }
}

// ---------------- router-only (fallback path needs sel_e/sel_w) ------------
__global__ __launch_bounds__(256) void router_k(
    const float* __restrict__ x, const float* __restrict__ Wr,
    int* __restrict__ sel_e, float* __restrict__ sel_w) {
  int t = blockIdx.x * 4 + (threadIdx.x >> 6);
  int lane = threadIdx.x & 63;
  const float* xp = x + (size_t)t * DMODEL;
  float p[NEXP];
#pragma unroll
  for (int e = 0; e < NEXP; e++) p[e] = 0.f;
#pragma unroll
  for (int i = 0; i < DMODEL / 64; i++) {
    float xv = xp[lane + i * 64];
#pragma unroll
    for (int e = 0; e < NEXP; e++) p[e] += xv * Wr[e * DMODEL + lane + i * 64];
  }
#pragma unroll
  for (int off = 32; off; off >>= 1) {
#pragma unroll
    for (int e = 0; e < NEXP; e++) p[e] += __shfl_xor(p[e], off);
  }
  if (lane == 0) {
    float l0 = -1e30f, l1 = -1e30f;
    int e0 = 0, e1 = 1;
#pragma unroll
    for (int e = 0; e < NEXP; e++) {
      if (p[e] > l0) { l1 = l0; e1 = e0; l0 = p[e]; e0 = e; }
      else if (p[e] > l1) { l1 = p[e]; e1 = e; }
    }
    float r = expf(l1 - l0);
    float inv = 1.f / (1.f + r);
    sel_e[t * 2] = e0;     sel_w[t * 2] = inv;
    sel_e[t * 2 + 1] = e1; sel_w[t * 2 + 1] = r * inv;
  }
}

extern "C" void kernel_launch(void* const* d_in, const int* in_sizes, int n_in,
                              void* d_out, int out_size, void* d_ws, size_t ws_size,
                              hipStream_t stream) {
  const float* residual = (const float*)d_in[0];
  const float* W_router = (const float*)d_in[1];
  const float* W_in = (const float*)d_in[2];
  const float* b_in = (const float*)d_in[3];
  const float* W_out = (const float*)d_in[4];
  const float* b_out = (const float*)d_in[5];
  float* out = (float*)d_out;

  char* ws = (char*)d_ws;
  int* meta = (int*)ws;
  size_t off = (size_t)1 << 20;
  f16* Xh = (f16*)(ws + off); off += (size_t)T_TOK * DMODEL * 2;       // 16 MB
  f16* Wih = (f16*)(ws + off); off += (size_t)NEXP * DMODEL * FFN * 2; // 64 MB
  f16* Woh = (f16*)(ws + off); off += (size_t)NEXP * DMODEL * FFN * 2; // 64 MB
  f16* H = (f16*)(ws + off); off += (size_t)NSLOT * FFN * 2;           // 128 MB
  off += 65536;                                                        // OOB slack
  bool fast = ws_size >= off;

  // Y0/Y1 alias Wih (dead after gemm1): 2 x 16384 x 1024 f16 = 64 MB exactly
  f16* Y0 = Wih;
  f16* Y1 = Wih + (size_t)NSLOT * DMODEL;

  int* sel_e = meta + 1024;
  float* sel_w = (float*)(meta + 1024 + NSLOT);
  int* row_tok = meta + 1024 + 2 * NSLOT;
  float* row_w = (float*)(meta + 1024 + 3 * NSLOT);
  int* inv = meta + 1024 + 4 * NSLOT;

  if (fast) {
    hipMemsetAsync(meta, 0, 512, stream);  // counts[8] + fill[8]
    prepA_k<<<4096 + T_TOK / 4, 256, 0, stream>>>(
        residual, W_router, W_in, sel_e, sel_w, Xh, Wih);
    count64_k<<<NSLOT / 256, 256, 0, stream>>>(sel_e, meta);
    scatter_k<<<NSLOT / 256, 256, 0, stream>>>(sel_e, sel_w, meta, meta + 64,
                                               row_tok, row_w, inv);
    gemm1_k<<<MAXT * 32 + 4096, 256, 0, stream>>>(Xh, Wih, b_in, H, meta,
                                                  W_out, Woh);
    gemm2_k<<<MAXT * 16, 256, 0, stream>>>(H, Woh, b_out, Y0, Y1, meta);
    combine_k<<<T_TOK / 4, 256, 0, stream>>>(Y0, Y1, inv, row_w, out);
  } else {
    hipMemsetAsync(d_out, 0, (size_t)out_size * sizeof(float), stream);
    router_k<<<T_TOK / 4, 256, 0, stream>>>(residual, W_router, sel_e, sel_w);
    naive_k<<<NSLOT, 256, 0, stream>>>(residual, W_in, b_in, W_out, b_out,
                                       sel_e, sel_w, out);
  }
}

// Round 20
// 507.885 us; speedup vs baseline: 1.0429x; 1.0004x over previous
//
#include <hip/hip_runtime.h>
#include <hip/hip_bf16.h>
#include <math.h>

#define T_TOK 8192
#define DMODEL 1024
#define FFN 4096
#define NEXP 8
#define NSLOT (T_TOK * 2)
#define MAXT 136  // sum ceil(c_e/128) <= 16384/128 + 8 = 136

typedef _Float16 f16;
typedef _Float16 half8 __attribute__((ext_vector_type(8)));
typedef _Float16 half4 __attribute__((ext_vector_type(4)));
typedef float f32x4 __attribute__((ext_vector_type(4)));
typedef unsigned int u32;

__device__ __forceinline__ void gll16(const void* g, void* l) {
  __builtin_amdgcn_global_load_lds(
      (const __attribute__((address_space(1))) u32*)g,
      (__attribute__((address_space(3))) u32*)l, 16, 0, 0);
}

// exact-erf gelu via A&S 7.1.26 (max abs err 1.5e-7), ~10 VALU ops
__device__ __forceinline__ float gelu_fast(float v) {
  float x = fabsf(v) * 0.70710678118654752f;
  float t = 1.0f / (1.0f + 0.3275911f * x);
  float poly = ((((1.061405429f * t - 1.453152027f) * t + 1.421413741f) * t -
                 0.284496736f) * t + 0.254829592f) * t;
  float erf_ = 1.0f - poly * __expf(-x * x);
  erf_ = copysignf(erf_, v);
  return 0.5f * v * (1.0f + erf_);
}

__device__ __forceinline__ float gelu_exact(float v) {
  return 0.5f * v * (1.0f + erff(v * 0.70710678118654752f));
}

// ---- tm -> (expert, row0, nrows) from counts[8]; 128-row tiles ------------
__device__ __forceinline__ bool decode_tile(const int* __restrict__ counts,
                                            int tm, int& e, int& row0,
                                            int& nrows) {
  int acc = 0, off = 0;
#pragma unroll
  for (int i = 0; i < NEXP; i++) {
    int c = counts[i];
    int nt = (c + 127) >> 7;
    if (tm < acc + nt) {
      int lt = tm - acc;
      e = i; row0 = off + lt * 128; nrows = min(128, c - lt * 128);
      return true;
    }
    acc += nt; off += c;
  }
  return false;
}

// ---- 128r x 64c transpose+convert tile, 256-thread, regular stores --------
__device__ __forceinline__ void transq_tile256(const float* __restrict__ ip,
                                               f16* __restrict__ op, int R, int C,
                                               int r0, int c0, char* smemraw) {
  float* tile = (float*)smemraw;  // [128][64] w/ chunk skew, 32 KB
  int tid = threadIdx.x;
#pragma unroll
  for (int p = 0; p < 8; p++) {
    int idx = tid + p * 256;
    int row = idx >> 4, q = idx & 15;
    f32x4 v = *(const f32x4*)(ip + (size_t)(r0 + row) * C + c0 + q * 4);
    int qs = (q + (row >> 3)) & 15;
    *(f32x4*)(tile + row * 64 + qs * 4) = v;
  }
  __syncthreads();
#pragma unroll
  for (int p = 0; p < 4; p++) {
    int idx = tid + p * 256;
    int c = idx >> 4, b = idx & 15;
    half8 h;
#pragma unroll
    for (int i = 0; i < 8; i++) {
      int row = b * 8 + i;
      int qs = (((c >> 2) + b) & 15);
      h[i] = (f16)tile[row * 64 + qs * 4 + (c & 3)];
    }
    *(half8*)(op + (size_t)(c0 + c) * R + r0 + b * 8) = h;
  }
}

// ======== prepA: blocks [0,4096) = W_in transpose; rest = router + x cvt ===
__global__ __launch_bounds__(256) void prepA_k(
    const float* __restrict__ x, const float* __restrict__ Wr,
    const float* __restrict__ Wi,
    int* __restrict__ sel_e, float* __restrict__ sel_w,
    f16* __restrict__ xh, f16* __restrict__ WiT) {
  __shared__ __align__(16) char smem[32768];
  if (blockIdx.x < 4096) {
    int e = blockIdx.x >> 9;
    int idx = blockIdx.x & 511;
    int rt = idx >> 6, ct = idx & 63;  // R=1024 -> 8 rt ; C=4096 -> 64 ct
    transq_tile256(Wi + (size_t)e * DMODEL * FFN, WiT + (size_t)e * DMODEL * FFN,
                   DMODEL, FFN, rt * 128, ct * 64, smem);
  } else {
    int rb = blockIdx.x - 4096;
    int t = rb * 4 + (threadIdx.x >> 6);
    int lane = threadIdx.x & 63;
    const float* xp = x + (size_t)t * DMODEL;
    f16* xhp = xh + (size_t)t * DMODEL;
    float p[NEXP];
#pragma unroll
    for (int e = 0; e < NEXP; e++) p[e] = 0.f;
#pragma unroll
    for (int q = 0; q < 4; q++) {
      f32x4 xv = *(const f32x4*)(xp + q * 256 + lane * 4);
      half4 h;
      h[0] = (f16)xv[0]; h[1] = (f16)xv[1]; h[2] = (f16)xv[2]; h[3] = (f16)xv[3];
      *(half4*)(xhp + q * 256 + lane * 4) = h;
#pragma unroll
      for (int e = 0; e < NEXP; e++) {
        const f32x4 wv = *(const f32x4*)(Wr + e * DMODEL + q * 256 + lane * 4);
        p[e] += xv[0] * wv[0] + xv[1] * wv[1] + xv[2] * wv[2] + xv[3] * wv[3];
      }
    }
#pragma unroll
    for (int off = 32; off; off >>= 1) {
#pragma unroll
      for (int e = 0; e < NEXP; e++) p[e] += __shfl_xor(p[e], off);
    }
    if (lane == 0) {
      float l0 = -1e30f, l1 = -1e30f;
      int e0 = 0, e1 = 1;
#pragma unroll
      for (int e = 0; e < NEXP; e++) {
        if (p[e] > l0) { l1 = l0; e1 = e0; l0 = p[e]; e0 = e; }
        else if (p[e] > l1) { l1 = p[e]; e1 = e; }
      }
      float r = expf(l1 - l0);
      float inv = 1.f / (1.f + r);
      sel_e[t * 2] = e0;     sel_w[t * 2] = inv;
      sel_e[t * 2 + 1] = e1; sel_w[t * 2 + 1] = r * inv;
    }
  }
}

// ---- count64: LDS-aggregated, 512 global atomics total --------------------
__global__ __launch_bounds__(256) void count64_k(const int* __restrict__ sel_e,
                                                 int* __restrict__ counts) {
  __shared__ int lc[NEXP];
  int tid = threadIdx.x;
  if (tid < NEXP) lc[tid] = 0;
  __syncthreads();
  int v = sel_e[blockIdx.x * 256 + tid];
  atomicAdd(&lc[v], 1);
  __syncthreads();
  if (tid < NEXP) atomicAdd(&counts[tid], lc[tid]);
}

// ---------------- scatter (offs derived in-register from counts) -----------
__global__ __launch_bounds__(256) void scatter_k(
    const int* __restrict__ sel_e, const float* __restrict__ sel_w,
    const int* __restrict__ counts, int* fill,
    int* __restrict__ row_tok, float* __restrict__ row_w,
    int* __restrict__ inv) {
  int s = blockIdx.x * 256 + threadIdx.x;
  int e = sel_e[s];
  int offs = 0;
#pragma unroll
  for (int i = 0; i < NEXP; i++) offs += (i < e) ? counts[i] : 0;
  int pos = atomicAdd(&fill[e], 1);
  int r = offs + pos;
  row_tok[r] = s >> 1;
  row_w[r] = sel_w[s];
  inv[s] = r;
}

// ============ GEMM1 (+ tail-fused W_out transpose), best config ===========
// 128x128, BK=64, 4 waves, single-buffer, 2 syncs/kt, zero-conflict XOR
// layout; wave-private barrier-free epilogue; NT H stores.
__global__ __launch_bounds__(256, 3) void gemm1_k(
    const f16* __restrict__ Xh, const f16* __restrict__ Wt,
    const float* __restrict__ b_in, f16* __restrict__ H,
    const int* __restrict__ meta,
    const float* __restrict__ Wo, f16* __restrict__ WoT) {
  __shared__ __align__(16) char smem[36864];  // staging 32K | epi 4x9216

  if (blockIdx.x >= MAXT * 32) {
    int bid = blockIdx.x - MAXT * 32;
    int e = bid >> 9;
    int idx = bid & 511;
    int rt = idx >> 4, ct = idx & 15;  // R=4096 -> 32 rt ; C=1024 -> 16 ct
    transq_tile256(Wo + (size_t)e * DMODEL * FFN, WoT + (size_t)e * DMODEL * FFN,
                   FFN, DMODEL, rt * 128, ct * 64, smem);
    return;
  }
  int bid2 = blockIdx.x;
  int xcd = bid2 & 7, bidx = bid2 >> 3;
  int wg = xcd * ((MAXT * 32) >> 3) + bidx;  // chunked-bijective XCD swizzle
  int tm = wg >> 5;            // slow: 32 consecutive wg share 256KB A panel
  int n0 = (wg & 31) * 128;
  int e, row0, nrows;
  if (!decode_tile(meta, tm, e, row0, nrows)) return;
  const int* row_tok = meta + 1024 + 2 * NSLOT;

  int tid = threadIdx.x, lane = tid & 63, wid = tid >> 6;
  int wrow = wid >> 1, wcol = wid & 1;
  int l15 = lane & 15, l4 = lane >> 4;

  u32 aoffs[4], boffs[4];
#pragma unroll
  for (int p = 0; p < 4; p++) {
    int L = tid + p * 256;
    int row = L >> 3, ch = L & 7;
    int cs = ch ^ (row & 7);
    aoffs[p] = (u32)(row_tok[min(row0 + row, NSLOT - 1)] * (DMODEL * 2) + cs * 16);
    boffs[p] = (u32)((e * FFN + n0 + row) * (DMODEL * 2) + cs * 16);
  }
  const char* gA = (const char*)Xh;
  const char* gB = (const char*)Wt;

  f32x4 acc[4][4];
#pragma unroll
  for (int m = 0; m < 4; m++)
#pragma unroll
    for (int n = 0; n < 4; n++) acc[m][n] = (f32x4)0.f;

  const int NT = DMODEL / 64;  // 16
  for (int kt = 0; kt < NT; ++kt) {
#pragma unroll
    for (int p = 0; p < 4; p++) {
      gll16(gA + aoffs[p], smem + (tid + p * 256) * 16);
      gll16(gB + boffs[p], smem + 16384 + (tid + p * 256) * 16);
      aoffs[p] += 128; boffs[p] += 128;
    }
    __syncthreads();  // drains vmcnt -> tile ready
#pragma unroll
    for (int s = 0; s < 2; s++) {
      int swz = ((s * 4 + l4) ^ (l15 & 7)) << 4;
      const char* pA = smem + (wrow * 64 + l15) * 128 + swz;
      const char* pB = smem + 16384 + (wcol * 64 + l15) * 128 + swz;
      half8 a[4], b[4];
#pragma unroll
      for (int i = 0; i < 4; i++) a[i] = *(const half8*)(pA + i * 2048);
#pragma unroll
      for (int j = 0; j < 4; j++) b[j] = *(const half8*)(pB + j * 2048);
#pragma unroll
      for (int i = 0; i < 4; i++)
#pragma unroll
        for (int j = 0; j < 4; j++)
          acc[i][j] = __builtin_amdgcn_mfma_f32_16x16x32_f16(a[i], b[j], acc[i][j], 0, 0, 0);
    }
    __syncthreads();  // all reads done before next stage overwrites
  }

  // wave-private epilogue (no barriers): gelu -> LDS [64 x 144B] -> NT stores
  char* wsm = smem + wid * 9216;
  float bias[4];
#pragma unroll
  for (int n = 0; n < 4; n++) bias[n] = b_in[e * FFN + n0 + wcol * 64 + n * 16 + l15];
#pragma unroll
  for (int m = 0; m < 4; m++)
#pragma unroll
    for (int n = 0; n < 4; n++)
#pragma unroll
      for (int j = 0; j < 4; j++) {
        int lrow = m * 16 + l4 * 4 + j;
        *(f16*)(wsm + lrow * 144 + (n * 16 + l15) * 2) =
            (f16)gelu_fast(acc[m][n][j] + bias[n]);
      }
#pragma unroll
  for (int p = 0; p < 8; ++p) {
    int lr = (lane >> 3) + p * 8;
    if (wrow * 64 + lr < nrows) {
      f32x4 v = *(const f32x4*)(wsm + lr * 144 + (lane & 7) * 16);
      __builtin_nontemporal_store(
          v, (f32x4*)(H + (size_t)(row0 + wrow * 64 + lr) * FFN + n0 +
                      wcol * 64 + (lane & 7) * 8));
    }
  }
}

// ============ GEMM2: Y[ks][slot] = H @ W_out (+b_out on ks0), f16, no atomics
__global__ __launch_bounds__(256, 3) void gemm2_k(
    const f16* __restrict__ H, const f16* __restrict__ Wt,
    const float* __restrict__ b_out, f16* __restrict__ Y0,
    f16* __restrict__ Y1, const int* __restrict__ meta) {
  int xcd = blockIdx.x & 7, bidx = blockIdx.x >> 3;
  int wg = xcd * (gridDim.x >> 3) + bidx;
  int tm = wg >> 4;            // slow
  int r4 = wg & 15;
  int n0 = (r4 & 7) * 128;     // fast: A panel reused across 8 blocks
  int ks = r4 >> 3;            // K half
  int e, row0, nrows;
  if (!decode_tile(meta, tm, e, row0, nrows)) return;

  __shared__ __align__(16) char smem[36864];

  int tid = threadIdx.x, lane = tid & 63, wid = tid >> 6;
  int wrow = wid >> 1, wcol = wid & 1;
  int l15 = lane & 15, l4 = lane >> 4;
  u32 k0b = (u32)(ks * (FFN / 2) * 2);   // byte offset of K half

  u32 aoffs[4], boffs[4];
#pragma unroll
  for (int p = 0; p < 4; p++) {
    int L = tid + p * 256;
    int row = L >> 3, ch = L & 7;
    int cs = ch ^ (row & 7);
    aoffs[p] = (u32)((u32)min(row0 + row, NSLOT - 1) * (FFN * 2) + k0b + cs * 16);
    boffs[p] = (u32)((u32)(e * DMODEL + n0 + row) * (FFN * 2) + k0b + cs * 16);
  }
  const char* gA = (const char*)H;
  const char* gB = (const char*)Wt;

  f32x4 acc[4][4];
#pragma unroll
  for (int m = 0; m < 4; m++)
#pragma unroll
    for (int n = 0; n < 4; n++) acc[m][n] = (f32x4)0.f;

  const int NT = (FFN / 2) / 64;  // 32
  for (int kt = 0; kt < NT; ++kt) {
#pragma unroll
    for (int p = 0; p < 4; p++) {
      gll16(gA + aoffs[p], smem + (tid + p * 256) * 16);
      gll16(gB + boffs[p], smem + 16384 + (tid + p * 256) * 16);
      aoffs[p] += 128; boffs[p] += 128;
    }
    __syncthreads();
#pragma unroll
    for (int s = 0; s < 2; s++) {
      int swz = ((s * 4 + l4) ^ (l15 & 7)) << 4;
      const char* pA = smem + (wrow * 64 + l15) * 128 + swz;
      const char* pB = smem + 16384 + (wcol * 64 + l15) * 128 + swz;
      half8 a[4], b[4];
#pragma unroll
      for (int i = 0; i < 4; i++) a[i] = *(const half8*)(pA + i * 2048);
#pragma unroll
      for (int j = 0; j < 4; j++) b[j] = *(const half8*)(pB + j * 2048);
#pragma unroll
      for (int i = 0; i < 4; i++)
#pragma unroll
        for (int j = 0; j < 4; j++)
          acc[i][j] = __builtin_amdgcn_mfma_f32_16x16x32_f16(a[i], b[j], acc[i][j], 0, 0, 0);
    }
    __syncthreads();
  }

  // wave-private epilogue: (acc+bias) -> f16 LDS -> NT row stores to Y[ks]
  f16* Y = ks ? Y1 : Y0;
  char* wsm = smem + wid * 9216;
  float bias[4];
#pragma unroll
  for (int n = 0; n < 4; n++)
    bias[n] = (ks == 0) ? b_out[e * DMODEL + n0 + wcol * 64 + n * 16 + l15] : 0.f;
#pragma unroll
  for (int m = 0; m < 4; m++)
#pragma unroll
    for (int n = 0; n < 4; n++)
#pragma unroll
      for (int j = 0; j < 4; j++) {
        int lrow = m * 16 + l4 * 4 + j;
        *(f16*)(wsm + lrow * 144 + (n * 16 + l15) * 2) =
            (f16)(acc[m][n][j] + bias[n]);
      }
#pragma unroll
  for (int p = 0; p < 8; ++p) {
    int lr = (lane >> 3) + p * 8;
    if (wrow * 64 + lr < nrows) {
      f32x4 v = *(const f32x4*)(wsm + lr * 144 + (lane & 7) * 16);
      __builtin_nontemporal_store(
          v, (f32x4*)(Y + (size_t)(row0 + wrow * 64 + lr) * DMODEL + n0 +
                      wcol * 64 + (lane & 7) * 8));
    }
  }
}

// ---------- combine: out[t] = w0*(Y0[r0]+Y1[r0]) + w1*(Y0[r1]+Y1[r1]) ------
__global__ __launch_bounds__(256) void combine_k(
    const f16* __restrict__ Y0, const f16* __restrict__ Y1,
    const int* __restrict__ inv, const float* __restrict__ row_w,
    float* __restrict__ out) {
  int t = blockIdx.x * 4 + (threadIdx.x >> 6);
  int lane = threadIdx.x & 63;
  int r0 = inv[2 * t], r1 = inv[2 * t + 1];
  float w0 = row_w[r0], w1 = row_w[r1];
  int d0 = lane * 16;
  const half8* a0 = (const half8*)(Y0 + (size_t)r0 * DMODEL + d0);
  const half8* a1 = (const half8*)(Y1 + (size_t)r0 * DMODEL + d0);
  const half8* b0 = (const half8*)(Y0 + (size_t)r1 * DMODEL + d0);
  const half8* b1 = (const half8*)(Y1 + (size_t)r1 * DMODEL + d0);
  float* op = out + (size_t)t * DMODEL + d0;
#pragma unroll
  for (int q = 0; q < 2; q++) {
    half8 x0 = a0[q], x1 = a1[q], y0 = b0[q], y1 = b1[q];
    float r[8];
#pragma unroll
    for (int i = 0; i < 8; i++)
      r[i] = w0 * ((float)x0[i] + (float)x1[i]) +
             w1 * ((float)y0[i] + (float)y1[i]);
    f32x4 v1 = {r[0], r[1], r[2], r[3]};
    f32x4 v2 = {r[4], r[5], r[6], r[7]};
    *(f32x4*)(op + q * 8) = v1;
    *(f32x4*)(op + q * 8 + 4) = v2;
  }
}

// ---------------- fallback (small workspace) -------------------------------
__global__ __launch_bounds__(256) void naive_k(
    const float* __restrict__ x, const float* __restrict__ W_in,
    const float* __restrict__ b_in, const float* __restrict__ W_out,
    const float* __restrict__ b_out, const int* __restrict__ sel_e,
    const float* __restrict__ sel_w, float* __restrict__ out) {
  int s = blockIdx.x;
  int t = s >> 1;
  int e = sel_e[s];
  float w = sel_w[s];
  __shared__ float xs[DMODEL];
  __shared__ float hs[FFN];
  int tid = threadIdx.x;
  for (int d = tid; d < DMODEL; d += 256) xs[d] = x[(size_t)t * DMODEL + d];
  __syncthreads();
  for (int f = tid; f < FFN; f += 256) {
    float a = b_in[e * FFN + f];
    const float* wp = W_in + (size_t)e * DMODEL * FFN + f;
    for (int d = 0; d < DMODEL; d++) a += xs[d] * wp[(size_t)d * FFN];
    hs[f] = gelu_exact(a);
  }
  __syncthreads();
  for (int d = tid; d < DMODEL; d += 256) {
    float a = b_out[e * DMODEL + d];
    const float* wp = W_out + (size_t)e * FFN * DMODEL + d;
    for (int f = 0; f < FFN; f++) a += hs[f] * wp[(size_t)f * DMODEL];
    atomicAdd(&out[(size_t)t * DMODEL + d], w * a);
  }
}

// ---------------- router-only (fallback path needs sel_e/sel_w) ------------
__global__ __launch_bounds__(256) void router_k(
    const float* __restrict__ x, const float* __restrict__ Wr,
    int* __restrict__ sel_e, float* __restrict__ sel_w) {
  int t = blockIdx.x * 4 + (threadIdx.x >> 6);
  int lane = threadIdx.x & 63;
  const float* xp = x + (size_t)t * DMODEL;
  float p[NEXP];
#pragma unroll
  for (int e = 0; e < NEXP; e++) p[e] = 0.f;
#pragma unroll
  for (int i = 0; i < DMODEL / 64; i++) {
    float xv = xp[lane + i * 64];
#pragma unroll
    for (int e = 0; e < NEXP; e++) p[e] += xv * Wr[e * DMODEL + lane + i * 64];
  }
#pragma unroll
  for (int off = 32; off; off >>= 1) {
#pragma unroll
    for (int e = 0; e < NEXP; e++) p[e] += __shfl_xor(p[e], off);
  }
  if (lane == 0) {
    float l0 = -1e30f, l1 = -1e30f;
    int e0 = 0, e1 = 1;
#pragma unroll
    for (int e = 0; e < NEXP; e++) {
      if (p[e] > l0) { l1 = l0; e1 = e0; l0 = p[e]; e0 = e; }
      else if (p[e] > l1) { l1 = p[e]; e1 = e; }
    }
    float r = expf(l1 - l0);
    float inv = 1.f / (1.f + r);
    sel_e[t * 2] = e0;     sel_w[t * 2] = inv;
    sel_e[t * 2 + 1] = e1; sel_w[t * 2 + 1] = r * inv;
  }
}

extern "C" void kernel_launch(void* const* d_in, const int* in_sizes, int n_in,
                              void* d_out, int out_size, void* d_ws, size_t ws_size,
                              hipStream_t stream) {
  const float* residual = (const float*)d_in[0];
  const float* W_router = (const float*)d_in[1];
  const float* W_in = (const float*)d_in[2];
  const float* b_in = (const float*)d_in[3];
  const float* W_out = (const float*)d_in[4];
  const float* b_out = (const float*)d_in[5];
  float* out = (float*)d_out;

  char* ws = (char*)d_ws;
  int* meta = (int*)ws;
  size_t off = (size_t)1 << 20;
  f16* Xh = (f16*)(ws + off); off += (size_t)T_TOK * DMODEL * 2;       // 16 MB
  f16* Wih = (f16*)(ws + off); off += (size_t)NEXP * DMODEL * FFN * 2; // 64 MB
  f16* Woh = (f16*)(ws + off); off += (size_t)NEXP * DMODEL * FFN * 2; // 64 MB
  f16* H = (f16*)(ws + off); off += (size_t)NSLOT * FFN * 2;           // 128 MB
  off += 65536;                                                        // OOB slack
  bool fast = ws_size >= off;

  // Y0/Y1 alias Wih (dead after gemm1): 2 x 16384 x 1024 f16 = 64 MB exactly
  f16* Y0 = Wih;
  f16* Y1 = Wih + (size_t)NSLOT * DMODEL;

  int* sel_e = meta + 1024;
  float* sel_w = (float*)(meta + 1024 + NSLOT);
  int* row_tok = meta + 1024 + 2 * NSLOT;
  float* row_w = (float*)(meta + 1024 + 3 * NSLOT);
  int* inv = meta + 1024 + 4 * NSLOT;

  if (fast) {
    hipMemsetAsync(meta, 0, 512, stream);  // counts[8] + fill[8]
    prepA_k<<<4096 + T_TOK / 4, 256, 0, stream>>>(
        residual, W_router, W_in, sel_e, sel_w, Xh, Wih);
    count64_k<<<NSLOT / 256, 256, 0, stream>>>(sel_e, meta);
    scatter_k<<<NSLOT / 256, 256, 0, stream>>>(sel_e, sel_w, meta, meta + 64,
                                               row_tok, row_w, inv);
    gemm1_k<<<MAXT * 32 + 4096, 256, 0, stream>>>(Xh, Wih, b_in, H, meta,
                                                  W_out, Woh);
    gemm2_k<<<MAXT * 16, 256, 0, stream>>>(H, Woh, b_out, Y0, Y1, meta);
    combine_k<<<T_TOK / 4, 256, 0, stream>>>(Y0, Y1, inv, row_w, out);
  } else {
    hipMemsetAsync(d_out, 0, (size_t)out_size * sizeof(float), stream);
    router_k<<<T_TOK / 4, 256, 0, stream>>>(residual, W_router, sel_e, sel_w);
    naive_k<<<NSLOT, 256, 0, stream>>>(residual, W_in, b_in, W_out, b_out,
                                       sel_e, sel_w, out);
  }
}